// Round 4
// baseline (1660.225 us; speedup 1.0000x reference)
//
#include <hip/hip_runtime.h>
#include <stdint.h>

#define TSTEPS 2048
#define L2E 1.4426950408889634f   // log2(e)

typedef _Float16 half8 __attribute__((ext_vector_type(8)));
typedef float    f32x4 __attribute__((ext_vector_type(4)));

// 4 waves per WG, one WG = 16 batch sequences.
// All 4 waves redundantly compute the same 8x mfma_f32_16x16x32_f16
// (gates[16x128] = h[16x32] @ Ws^T); wave w applies activations only to
// D-tile batch-row r == w (2 cells/lane: units {cidx, cidx+16} of batch
// quad*4+w). Discarded D rows carry garbage in the C operand — harmless,
// rows are independent. This turns 512 latency-bound waves into 2048
// (2/SIMD on all 1024 SIMDs), spreading the quarter-rate trans-pipe work
// (the real floor) across the whole chip.
// Weights pre-scaled by -log2e (i,f,o) / +2log2e (g) so v_exp_f32 (2^x)
// consumes the accumulator directly.
// h feedback: double-buffered f16 LDS [2][16][36] (72B stride), one
// __syncthreads per step.
extern "C" __global__ void __launch_bounds__(256)
lstm_mfma4(const float* __restrict__ x,     // [B, T]
           const float* __restrict__ W_ih,  // [128]
           const float* __restrict__ W_hh,  // [128, 32]
           const float* __restrict__ b_ih,  // [128]
           const float* __restrict__ b_hh,  // [128]
           const float* __restrict__ W3,    // [32, 32]
           const float* __restrict__ b3,    // [32]
           const float* __restrict__ W4,    // [32]
           const float* __restrict__ b4,    // [1]
           float* __restrict__ out)         // [B]
{
    const int tid   = threadIdx.x;
    const int w     = tid >> 6;        // wave 0..3 == batch-row slice
    const int lane  = tid & 63;
    const int cidx  = lane & 15;
    const int quad  = lane >> 4;
    const int batch0 = blockIdx.x * 16;

    __shared__ _Float16 hsh[2][16 * 36];   // double buffer, 72B row stride

    // ---- B fragments (same for all waves): tile n covers gates 16n..16n+15
    half8 bfrag[8];
    float wihs[8], biass[8];
    #pragma unroll
    for (int n = 0; n < 8; ++n) {
        const int g = 16 * n + cidx;
        const float s = (n == 4 || n == 5) ? (2.0f * L2E) : (-L2E);
        const float* wr = W_hh + g * 32 + quad * 8;
        float4 w0 = *(const float4*)(wr);
        float4 w1 = *(const float4*)(wr + 4);
        half8 hb;
        hb[0] = (_Float16)(w0.x * s); hb[1] = (_Float16)(w0.y * s);
        hb[2] = (_Float16)(w0.z * s); hb[3] = (_Float16)(w0.w * s);
        hb[4] = (_Float16)(w1.x * s); hb[5] = (_Float16)(w1.y * s);
        hb[6] = (_Float16)(w1.z * s); hb[7] = (_Float16)(w1.w * s);
        bfrag[n] = hb;
        wihs[n]  = W_ih[g] * s;
        biass[n] = (b_ih[g] + b_hh[g]) * s;
    }

    // this wave's batch row within the tile
    const int myb = quad * 4 + w;          // 0..15
    float cst[2] = {0.0f, 0.0f};           // c for units {cidx, cidx+16}

    // zero-init buffer 0: each wave zeroes exactly its own cells
    hsh[0][myb * 36 + cidx]      = (_Float16)0.0f;
    hsh[0][myb * 36 + 16 + cidx] = (_Float16)0.0f;
    __syncthreads();

    // x for this lane's single batch row
    const float* xp = x + (size_t)(batch0 + myb) * TSTEPS;
    float4 xnext = *(const float4*)(xp);

    f32x4 acc[8];
    #pragma unroll
    for (int n = 0; n < 8; ++n) acc[n] = (f32x4){0.f, 0.f, 0.f, 0.f};

    const char* hb0 = (const char*)hsh[0];
    const char* hb1 = (const char*)hsh[1];
    const int abyte = cidx * 72 + quad * 16;

    for (int t0 = 0; t0 < TSTEPS; t0 += 4) {
        float4 xc = xnext;
        if (t0 + 4 < TSTEPS) xnext = *(const float4*)(xp + t0 + 4);
        #pragma unroll
        for (int tt = 0; tt < 4; ++tt) {
            const int p = (t0 + tt) & 1;
            const char* rbuf = p ? hb1 : hb0;
            _Float16*   wbuf = p ? hsh[0] : hsh[1];

            // A fragment: h[m=cidx][k=quad*8+q] from read buffer
            union { uint2 u2[2]; half8 h; } af;
            af.u2[0] = *(const uint2*)(rbuf + abyte);
            af.u2[1] = *(const uint2*)(rbuf + abyte + 8);

            const float xs = ((const float*)&xc)[tt];
            // init only our batch-row; other rows keep garbage (discarded)
            #pragma unroll
            for (int n = 0; n < 8; ++n)
                acc[n][w] = fmaf(xs, wihs[n], biass[n]);

            #pragma unroll
            for (int n = 0; n < 8; ++n)
                acc[n] = __builtin_amdgcn_mfma_f32_16x16x32_f16(
                             af.h, bfrag[n], acc[n], 0, 0, 0);

            // activations for our 2 cells (units cidx, cidx+16 of batch myb)
            #pragma unroll
            for (int h2 = 0; h2 < 2; ++h2) {
                float ei = __builtin_amdgcn_exp2f(acc[0 + h2][w]);
                float ef = __builtin_amdgcn_exp2f(acc[2 + h2][w]);
                float eg = __builtin_amdgcn_exp2f(acc[4 + h2][w]);
                float eo = __builtin_amdgcn_exp2f(acc[6 + h2][w]);
                float si = __builtin_amdgcn_rcpf(1.0f + ei);
                float sf = __builtin_amdgcn_rcpf(1.0f + ef);
                float tg = fmaf(-2.0f, __builtin_amdgcn_rcpf(1.0f + eg), 1.0f);
                float so = __builtin_amdgcn_rcpf(1.0f + eo);
                float cn = fmaf(sf, cst[h2], si * tg);
                cst[h2] = cn;
                float ec = __builtin_amdgcn_exp2f(cn * (2.0f * L2E));
                float tc = fmaf(-2.0f, __builtin_amdgcn_rcpf(1.0f + ec), 1.0f);
                wbuf[myb * 36 + h2 * 16 + cidx] = (_Float16)(so * tc);
            }
            __syncthreads();
        }
    }

    // ---- head (wave 0 only): final h is in hsh[0] ----
    if (w == 0) {
        float hk[32];
        #pragma unroll
        for (int k = 0; k < 32; ++k) hk[k] = (float)hsh[0][cidx * 36 + k];

        float v = 0.0f;
        #pragma unroll
        for (int j = 0; j < 32; ++j) {
            const float4* w3r = (const float4*)(W3 + j * 32);
            float a = b3[j];
            #pragma unroll
            for (int q = 0; q < 8; ++q) {
                float4 wv = w3r[q];
                a = fmaf(hk[4 * q + 0], wv.x, a);
                a = fmaf(hk[4 * q + 1], wv.y, a);
                a = fmaf(hk[4 * q + 2], wv.z, a);
                a = fmaf(hk[4 * q + 3], wv.w, a);
            }
            a = fmaxf(a, 0.0f);
            v = fmaf(a, W4[j], v);
        }
        if (quad == 0) {
            float e = __builtin_amdgcn_exp2f(-(v + b4[0]) * L2E);
            out[batch0 + cidx] = __builtin_amdgcn_rcpf(1.0f + e);
        }
    }
}

extern "C" void kernel_launch(void* const* d_in, const int* in_sizes, int n_in,
                              void* d_out, int out_size, void* d_ws, size_t ws_size,
                              hipStream_t stream) {
    const float* x    = (const float*)d_in[0];
    const float* W_ih = (const float*)d_in[1];
    const float* W_hh = (const float*)d_in[2];
    const float* b_ih = (const float*)d_in[3];
    const float* b_hh = (const float*)d_in[4];
    const float* W3   = (const float*)d_in[5];
    const float* b3   = (const float*)d_in[6];
    const float* W4   = (const float*)d_in[7];
    const float* b4   = (const float*)d_in[8];
    float* out = (float*)d_out;

    const int batches = out_size;          // 8192
    const int blocks  = batches / 16;      // 512 WGs x 256 thr = 2048 waves
    lstm_mfma4<<<blocks, 256, 0, stream>>>(x, W_ih, W_hh, b_ih, b_hh,
                                           W3, b3, W4, b4, out);
}

// Round 5
// 1228.682 us; speedup vs baseline: 1.3512x; 1.3512x over previous
//
#include <hip/hip_runtime.h>
#include <stdint.h>

#define TSTEPS 2048
#define L2E 1.4426950408889634f   // log2(e)

typedef _Float16 half8 __attribute__((ext_vector_type(8)));
typedef float    f32x4 __attribute__((ext_vector_type(4)));

// One wave (WG=64) owns 4 batch sequences end-to-end. No barriers, no
// cross-wave traffic, no runtime-indexed vectors (rule #20).
//
// A-fragment uses ROW-DUPLICATED h: A[m][k] = h[batch m>>2][unit k], so the
// 16x16x32 MFMA D-tile (row=(lane>>4)*4+r, col=lane&15; m89-verified) holds
// gates[batch quad][gate 16n+cidx] identically in regs r=0..3 -> every lane
// reads its 2 live cells at COMPILE-TIME reg 0 (batch=quad, units
// {cidx,cidx+16}). 2 cells/lane spreads the quarter-rate trans work
// (5 exp + 5 rcp per cell) evenly over all 64 lanes of all 2048 waves.
// Unused acc rows accumulate garbage harmlessly (rows independent, fp32,
// zero-initialized so never NaN).
//
// Weights pre-scaled by -log2e (i,f,o) / +2log2e (g) so v_exp_f32 (2^x)
// consumes the MFMA accumulator directly:
//   sigmoid(a) = rcp(1 + 2^(-a*log2e)),  tanh(a) = 1 - 2*rcp(1 + 2^(2a*log2e))
//
// h feedback: 256 B LDS tile h[4][32] f16, stride 64 B. A-read: one
// ds_read_b128/lane at (cidx>>2)*64 + quad*16 -> 16 blocks x 4-lane
// broadcast, exact 2-way banking (free, m136). Intra-wave in-order DS pipe
// + lgkmcnt(0) fence (r2/r3-verified pattern) gives step ordering.
extern "C" __global__ void __launch_bounds__(64)
lstm_w4(const float* __restrict__ x,     // [B, T]
        const float* __restrict__ W_ih,  // [128]
        const float* __restrict__ W_hh,  // [128, 32]
        const float* __restrict__ b_ih,  // [128]
        const float* __restrict__ b_hh,  // [128]
        const float* __restrict__ W3,    // [32, 32]
        const float* __restrict__ b3,    // [32]
        const float* __restrict__ W4,    // [32]
        const float* __restrict__ b4,    // [1]
        float* __restrict__ out)         // [B]
{
    const int lane = threadIdx.x;
    const int cidx = lane & 15;
    const int quad = lane >> 4;
    const int wb   = blockIdx.x * 4;       // 4 batches per wave

    __shared__ _Float16 hsh[4 * 32];       // h[group][unit], 64B row stride

    // ---- B fragments: tile n covers gate rows 16n..16n+15 ----
    // lane holds B[k = quad*8+q][gatecol = 16n+cidx] = s * W_hh[gatecol][k]
    half8 bfrag[8];
    float wihs[8], biass[8];
    #pragma unroll
    for (int n = 0; n < 8; ++n) {
        const int g = 16 * n + cidx;
        const float s = (n == 4 || n == 5) ? (2.0f * L2E) : (-L2E);
        const float* wr = W_hh + g * 32 + quad * 8;
        float4 w0 = *(const float4*)(wr);
        float4 w1 = *(const float4*)(wr + 4);
        half8 hb;
        hb[0] = (_Float16)(w0.x * s); hb[1] = (_Float16)(w0.y * s);
        hb[2] = (_Float16)(w0.z * s); hb[3] = (_Float16)(w0.w * s);
        hb[4] = (_Float16)(w1.x * s); hb[5] = (_Float16)(w1.y * s);
        hb[6] = (_Float16)(w1.z * s); hb[7] = (_Float16)(w1.w * s);
        bfrag[n] = hb;
        wihs[n]  = W_ih[g] * s;
        biass[n] = (b_ih[g] + b_hh[g]) * s;
    }

    // c state for this lane's 2 cells: units {cidx, cidx+16} of batch quad
    float cst[2] = {0.0f, 0.0f};

    // zero h(0): each lane writes exactly its own 2 cells
    hsh[quad * 32 + cidx]      = (_Float16)0.0f;
    hsh[quad * 32 + 16 + cidx] = (_Float16)0.0f;
    asm volatile("s_waitcnt lgkmcnt(0)" ::: "memory");

    // x for this lane's batch (uniform across the 16 lanes of a quad)
    const float* xp = x + (size_t)(wb + quad) * TSTEPS;
    float4 xnext = *(const float4*)(xp);

    f32x4 acc[8];
    #pragma unroll
    for (int n = 0; n < 8; ++n) acc[n] = (f32x4){0.f, 0.f, 0.f, 0.f};

    const char* hb8 = (const char*)hsh;
    const int abyte = (cidx >> 2) * 64 + quad * 16;  // A[m=cidx][k=quad*8+j]

    for (int t0 = 0; t0 < TSTEPS; t0 += 4) {
        float4 xc = xnext;
        if (t0 + 4 < TSTEPS) xnext = *(const float4*)(xp + t0 + 4);
        #pragma unroll
        for (int tt = 0; tt < 4; ++tt) {
            // A fragment: duplicated-row h read, one ds_read_b128
            union { uint4 u4; half8 h; } af;
            af.u4 = *(const uint4*)(hb8 + abyte);

            const float xs = ((const float*)&xc)[tt];
            // init only reg 0 (live rows); regs 1-3 keep accumulated garbage
            #pragma unroll
            for (int n = 0; n < 8; ++n)
                acc[n][0] = fmaf(xs, wihs[n], biass[n]);

            #pragma unroll
            for (int n = 0; n < 8; ++n)
                acc[n] = __builtin_amdgcn_mfma_f32_16x16x32_f16(
                             af.h, bfrag[n], acc[n], 0, 0, 0);

            // activations: units cidx (h2=0) and cidx+16 (h2=1) of batch quad
            #pragma unroll
            for (int h2 = 0; h2 < 2; ++h2) {
                float ei = __builtin_amdgcn_exp2f(acc[0 + h2][0]);
                float ef = __builtin_amdgcn_exp2f(acc[2 + h2][0]);
                float eg = __builtin_amdgcn_exp2f(acc[4 + h2][0]);
                float eo = __builtin_amdgcn_exp2f(acc[6 + h2][0]);
                float si = __builtin_amdgcn_rcpf(1.0f + ei);
                float sf = __builtin_amdgcn_rcpf(1.0f + ef);
                float tg = fmaf(-2.0f, __builtin_amdgcn_rcpf(1.0f + eg), 1.0f);
                float so = __builtin_amdgcn_rcpf(1.0f + eo);
                float cn = fmaf(sf, cst[h2], si * tg);
                cst[h2] = cn;
                float ec = __builtin_amdgcn_exp2f(cn * (2.0f * L2E));
                float tc = fmaf(-2.0f, __builtin_amdgcn_rcpf(1.0f + ec), 1.0f);
                hsh[quad * 32 + h2 * 16 + cidx] = (_Float16)(so * tc);
            }
            // in-order DS pipe: drain writes before next step's A-read;
            // "memory" clobber orders the surrounding LDS accesses
            asm volatile("s_waitcnt lgkmcnt(0)" ::: "memory");
        }
    }

    // ---- head: 4 batches; lane j=lane&31, batches g0 and g0+2 (g0=lane>>5)
    const int j  = lane & 31;
    const int g0 = lane >> 5;
    float a0 = b3[j], a1 = b3[j];
    #pragma unroll
    for (int k = 0; k < 32; ++k) {
        float w3v = W3[j * 32 + k];
        a0 = fmaf((float)hsh[g0 * 32 + k],       w3v, a0);
        a1 = fmaf((float)hsh[(g0 + 2) * 32 + k], w3v, a1);
    }
    a0 = fmaxf(a0, 0.0f);
    a1 = fmaxf(a1, 0.0f);
    const float w4 = W4[j];
    float v0 = a0 * w4, v1 = a1 * w4;
    // reduce within each 32-lane half (masks <32 stay in-half at width 64)
    #pragma unroll
    for (int off = 16; off >= 1; off >>= 1) {
        v0 += __shfl_xor(v0, off);
        v1 += __shfl_xor(v1, off);
    }
    if ((lane & 31) == 0) {
        float e0 = __builtin_amdgcn_exp2f(-(v0 + b4[0]) * L2E);
        float e1 = __builtin_amdgcn_exp2f(-(v1 + b4[0]) * L2E);
        out[wb + g0]     = __builtin_amdgcn_rcpf(1.0f + e0);
        out[wb + g0 + 2] = __builtin_amdgcn_rcpf(1.0f + e1);
    }
}

extern "C" void kernel_launch(void* const* d_in, const int* in_sizes, int n_in,
                              void* d_out, int out_size, void* d_ws, size_t ws_size,
                              hipStream_t stream) {
    const float* x    = (const float*)d_in[0];
    const float* W_ih = (const float*)d_in[1];
    const float* W_hh = (const float*)d_in[2];
    const float* b_ih = (const float*)d_in[3];
    const float* b_hh = (const float*)d_in[4];
    const float* W3   = (const float*)d_in[5];
    const float* b3   = (const float*)d_in[6];
    const float* W4   = (const float*)d_in[7];
    const float* b4   = (const float*)d_in[8];
    float* out = (float*)d_out;

    const int batches = out_size;          // 8192
    const int blocks  = batches / 4;       // 2048 independent waves
    lstm_w4<<<blocks, 64, 0, stream>>>(x, W_ih, W_hh, b_ih, b_hh,
                                       W3, b3, W4, b4, out);
}